// Round 1
// baseline (701.864 us; speedup 1.0000x reference)
//
#include <hip/hip_runtime.h>

typedef unsigned short u16;
typedef unsigned int   u32;
typedef _Float16       f16;

#define M_DIM 4096
#define K_DIM 4096
#define N_DIM 11008
#define NQ8   (N_DIM / 8)

typedef f16   f16x8 __attribute__((ext_vector_type(8)));
typedef f16   f16x2 __attribute__((ext_vector_type(2)));
typedef float f32x4 __attribute__((ext_vector_type(4)));

typedef __attribute__((address_space(1))) void GV;
typedef __attribute__((address_space(3))) void LV;

#define SFENCE() __builtin_amdgcn_sched_barrier(0)
#define BAR()    __builtin_amdgcn_s_barrier()

__device__ __forceinline__ u32 pk2(float lo, float hi) {
    // v_cvt_pkrtz_f16_f32; exact for fp16-representable values (x is fp16-origin).
    return __builtin_bit_cast(u32, __builtin_amdgcn_cvt_pkrtz(lo, hi));
}

// x -> fp16 with per-8-group k-permutation: pairs (k0,k4),(k1,k5),(k2,k6),(k3,k7),
// matching the B-side nibble pairing ((q>>4j) gives nibbles j and j+4 in one mask).
__global__ __launch_bounds__(256) void cvt_x(const float* __restrict__ x, f16* __restrict__ xh) {
    const size_t t = (size_t)blockIdx.x * 256 + threadIdx.x;  // one 8-group per thread
    const float4* p = (const float4*)(x + t * 8);
    float4 a0 = p[0], a1 = p[1];
    uint4 v;
    v.x = pk2(a0.x, a1.x); v.y = pk2(a0.y, a1.y);
    v.z = pk2(a0.z, a1.z); v.w = pk2(a0.w, a1.w);
    *(uint4*)(xh + t * 8) = v;
}

// Dequant one qweight dword -> 8 fp16 (pair order), b2 = -(1025+z) exact, s2 = scale.
// ((q>>4j)&0x000F000F)|0x64006400 = fp16x2(1024+wj, 1024+w(j+4)) exact;
// pk_add exact integer bias; pk_mul = single fp16 rounding (= reference).
__device__ __forceinline__ uint4 dq8(u32 q, f16x2 b2, f16x2 s2) {
    u32 pk[4];
    #pragma unroll
    for (int j = 0; j < 4; j++) {
        const u32 mb = ((q >> (4 * j)) & 0x000F000Fu) | 0x64006400u;
        f16x2 v2 = __builtin_bit_cast(f16x2, mb);
        f16x2 w2 = (v2 + b2) * s2;
        pk[j] = __builtin_bit_cast(u32, w2);
    }
    uint4 r; r.x = pk[0]; r.y = pk[1]; r.z = pk[2]; r.w = pk[3];
    return r;
}

// ================= 256x256x64 8-phase kernel =================
#define BM 256
#define BN 256
#define BK 64
#define NKT (K_DIM / BK)   // 64

template<int AI, int CJ>
__device__ __forceinline__ void mfma_block(f32x4 (&acc)[8][4], const f16x8 (&af)[4][2],
                                           const f16x8 (&bf)[2][2]) {
    #pragma unroll
    for (int mf = 0; mf < 4; ++mf)
        #pragma unroll
        for (int nf = 0; nf < 2; ++nf)
            #pragma unroll
            for (int ks = 0; ks < 2; ++ks)
                acc[AI + mf][CJ + nf] = __builtin_amdgcn_mfma_f32_16x16x32_f16(
                    af[mf][ks], bf[nf][ks], acc[AI + mf][CJ + nf], 0, 0, 0);
}

#define MFMA_PHASE(AI, BF, CJ)                \
    BAR();                                    \
    __builtin_amdgcn_s_setprio(1);            \
    mfma_block<AI, CJ>(acc, af, BF);          \
    __builtin_amdgcn_s_setprio(0);            \
    BAR();

// LDS layout (both tiles): tile[row][chunk ^ (row&7)], chunk = 16B k-chunk (8/row).
// A: glds dest linear in tid (HW wave-uniform+lane*16 rule), source pre-inverse-swizzled.
// B: reg-dequant + swizzled ds_write_b128. All quarter-wave patterns land 2-way (free).
__global__ __launch_bounds__(512, 2)
void gptq_gemm_big(const f16* __restrict__ xh, const int* __restrict__ qw,
                   const float* __restrict__ sc, const int* __restrict__ qz,
                   float* __restrict__ out)
{
    __shared__ __align__(16) f16 As[2][BM * BK];
    __shared__ __align__(16) f16 Bs[2][BN * BK];

    const int tid  = threadIdx.x;
    const int lane = tid & 63;
    const int wave = tid >> 6;
    const int quad = lane >> 4;
    const int l15  = lane & 15;
    const int sw   = l15 & 7;
    const int wm   = (wave >> 2) * 128;   // 2 waves in M
    const int wn   = (wave & 3) * 64;     // 4 waves in N

    // bijective XCD swizzle: 688 blocks = 8 * 86; each XCD gets 2 full M-rows of N-blocks.
    const int bid0 = blockIdx.y * 43 + blockIdx.x;
    const int bid  = (bid0 & 7) * 86 + (bid0 >> 3);
    const int n0 = (bid % 43) * BN;
    const int m0 = (bid / 43) * BM;

    const int cko[2] = { (quad ^ sw) * 8, ((4 + quad) ^ sw) * 8 };  // frag chunk offs (halfs)

    // ---- A staging: 4 slots/thread; slot s=(tid+j*512) -> row s>>3, lds-chunk s&7,
    //      global chunk = (s&7)^(row&7). row&7 and tid&7-xor constant over j.
    const int arow = tid >> 3;
    const int acnk = (tid & 7) ^ (arow & 7);
    const f16* ag[4];
    #pragma unroll
    for (int j = 0; j < 4; ++j)
        ag[j] = xh + (size_t)(m0 + j * 64 + arow) * K_DIM + acnk * 8;

    // ---- B dequant: thread owns column bn, qweight rows bsub*4+i of each k-tile.
    const int bn   = tid >> 1;
    const int bsub = tid & 1;
    const int gn   = n0 + bn;
    const int zsh  = (gn & 7) * 4;
    const int* qwp[4];
    #pragma unroll
    for (int i = 0; i < 4; ++i)
        qwp[i] = qw + (size_t)(bsub * 4 + i) * N_DIM + gn;
    const int*   qzp = qz + (gn >> 3);
    const float* scp = sc + gn;
    int bwo[4];
    #pragma unroll
    for (int i = 0; i < 4; ++i)
        bwo[i] = (bn * 8 + ((bsub * 4 + i) ^ (bn & 7))) * 8;   // halfs

    f32x4 acc[8][4];
    #pragma unroll
    for (int i = 0; i < 8; ++i)
        #pragma unroll
        for (int j = 0; j < 4; ++j)
            acc[i][j] = (f32x4){0.f, 0.f, 0.f, 0.f};

    u32 bq_c[4]; u32 zq_c; float sv_c;   // B pipeline regs (tile t+1)

    // ================= prologue: stage tile 0; preload tile-1 B =================
    {
        const u32 zq0  = (u32)qzp[0];
        const float sv0 = scp[0];
        u32 bq0[4];
        #pragma unroll
        for (int i = 0; i < 4; ++i) bq0[i] = (u32)qwp[i][0];
        SFENCE();
        #pragma unroll
        for (int j = 0; j < 4; ++j)
            __builtin_amdgcn_global_load_lds((GV*)ag[j], (LV*)(&As[0][0] + (tid + j * 512) * 8), 16, 0, 0);
        SFENCE();
        #pragma unroll
        for (int i = 0; i < 4; ++i) bq_c[i] = (u32)qwp[i][(size_t)8 * N_DIM];
        zq_c = (u32)qzp[0];
        sv_c = scp[0];
        const int z1 = (int)((zq0 >> zsh) & 15u) + 1;
        const f16 sh = (f16)sv0;
        const f16 bh = (f16)(-(float)(1024 + z1));
        const f16x2 s2 = {sh, sh}, b2 = {bh, bh};
        #pragma unroll
        for (int i = 0; i < 4; ++i)
            *(uint4*)(&Bs[0][0] + bwo[i]) = dq8(bq0[i], b2, s2);
        SFENCE();
        asm volatile("s_waitcnt vmcnt(6)" ::: "memory");   // 4 glds done; tile-1 B in flight
        asm volatile("s_waitcnt lgkmcnt(0)" ::: "memory");
        BAR();
    }

    // ================= main loop: compute tile t (buf b), stage t+1 (buf b^1) ======
    #pragma unroll 1
    for (int t = 0; t < NKT - 1; ++t) {
        const int b = t & 1;
        const f16* Ab = &As[b][0];
        const f16* Bb = &Bs[b][0];
        f16* Ad = &As[b ^ 1][0];
        f16* Bd = &Bs[b ^ 1][0];

        const int z1 = (int)((zq_c >> zsh) & 15u) + 1;
        const f16 sh = (f16)sv_c;
        const f16 bh = (f16)(-(float)(1024 + z1));
        const f16x2 s2 = {sh, sh}, b2 = {bh, bh};

        f16x8 af[4][2], bf0[2][2], bf1[2][2];

        // ---------- phase 0: read A(mh0)+B(nh0); glds half 0; dequant dw 0,1 ----------
        #pragma unroll
        for (int mf = 0; mf < 4; ++mf)
            #pragma unroll
            for (int ks = 0; ks < 2; ++ks)
                af[mf][ks] = *(const f16x8*)(Ab + (wm + mf * 16 + l15) * 64 + cko[ks]);
        #pragma unroll
        for (int nf = 0; nf < 2; ++nf)
            #pragma unroll
            for (int ks = 0; ks < 2; ++ks)
                bf0[nf][ks] = *(const f16x8*)(Bb + (wn + nf * 16 + l15) * 64 + cko[ks]);
        SFENCE();
        __builtin_amdgcn_global_load_lds((GV*)(ag[0] + (t + 1) * BK), (LV*)(Ad + tid * 8), 16, 0, 0);
        __builtin_amdgcn_global_load_lds((GV*)(ag[1] + (t + 1) * BK), (LV*)(Ad + (tid + 512) * 8), 16, 0, 0);
        SFENCE();
        *(uint4*)(Bd + bwo[0]) = dq8(bq_c[0], b2, s2);
        *(uint4*)(Bd + bwo[1]) = dq8(bq_c[1], b2, s2);
        MFMA_PHASE(0, bf0, 0)

        // ---------- phase 1: read B(nh1); glds half 1; dequant dw 2,3 ----------
        #pragma unroll
        for (int nf = 0; nf < 2; ++nf)
            #pragma unroll
            for (int ks = 0; ks < 2; ++ks)
                bf1[nf][ks] = *(const f16x8*)(Bb + (wn + 32 + nf * 16 + l15) * 64 + cko[ks]);
        SFENCE();
        __builtin_amdgcn_global_load_lds((GV*)(ag[2] + (t + 1) * BK), (LV*)(Ad + (tid + 1024) * 8), 16, 0, 0);
        __builtin_amdgcn_global_load_lds((GV*)(ag[3] + (t + 1) * BK), (LV*)(Ad + (tid + 1536) * 8), 16, 0, 0);
        SFENCE();
        *(uint4*)(Bd + bwo[2]) = dq8(bq_c[2], b2, s2);
        *(uint4*)(Bd + bwo[3]) = dq8(bq_c[3], b2, s2);
        MFMA_PHASE(0, bf1, 2)

        // ---------- phase 2: read A(mh1); issue B loads for tile t+2 ----------
        #pragma unroll
        for (int mf = 0; mf < 4; ++mf)
            #pragma unroll
            for (int ks = 0; ks < 2; ++ks)
                af[mf][ks] = *(const f16x8*)(Ab + (wm + 64 + mf * 16 + l15) * 64 + cko[ks]);
        {
            const int t2 = (t + 2 < NKT) ? (t + 2) : (NKT - 1);   // clamp keeps vmcnt pattern
            #pragma unroll
            for (int i = 0; i < 4; ++i)
                bq_c[i] = (u32)qwp[i][(size_t)(t2 * 8) * N_DIM];
            zq_c = (u32)qzp[(size_t)(t2 >> 1) * NQ8];
            sv_c = scp[(size_t)(t2 >> 1) * N_DIM];
        }
        MFMA_PHASE(4, bf1, 2)

        // ---------- phase 3: counted drain (glds retire; 6 B/param loads stay in flight) --
        SFENCE();
        asm volatile("s_waitcnt vmcnt(6)" ::: "memory");
        asm volatile("s_waitcnt lgkmcnt(0)" ::: "memory");
        MFMA_PHASE(4, bf0, 0)
    }

    // ================= final tile (buf 1), compute only =================
    {
        const f16* Ab = &As[1][0];
        const f16* Bb = &Bs[1][0];
        f16x8 af[4][2], bf0[2][2], bf1[2][2];
        #pragma unroll
        for (int nf = 0; nf < 2; ++nf)
            #pragma unroll
            for (int ks = 0; ks < 2; ++ks) {
                bf0[nf][ks] = *(const f16x8*)(Bb + (wn + nf * 16 + l15) * 64 + cko[ks]);
                bf1[nf][ks] = *(const f16x8*)(Bb + (wn + 32 + nf * 16 + l15) * 64 + cko[ks]);
            }
        #pragma unroll
        for (int mh = 0; mh < 2; ++mh) {
            #pragma unroll
            for (int mf = 0; mf < 4; ++mf)
                #pragma unroll
                for (int ks = 0; ks < 2; ++ks)
                    af[mf][ks] = *(const f16x8*)(Ab + (wm + mh * 64 + mf * 16 + l15) * 64 + cko[ks]);
            #pragma unroll
            for (int mf = 0; mf < 4; ++mf)
                #pragma unroll
                for (int nf = 0; nf < 2; ++nf)
                    #pragma unroll
                    for (int ks = 0; ks < 2; ++ks) {
                        acc[mh * 4 + mf][nf]     = __builtin_amdgcn_mfma_f32_16x16x32_f16(
                            af[mf][ks], bf0[nf][ks], acc[mh * 4 + mf][nf], 0, 0, 0);
                        acc[mh * 4 + mf][2 + nf] = __builtin_amdgcn_mfma_f32_16x16x32_f16(
                            af[mf][ks], bf1[nf][ks], acc[mh * 4 + mf][2 + nf], 0, 0, 0);
                    }
        }
    }

    // epilogue: C/D layout col=lane&15, row=quad*4+r
    #pragma unroll
    for (int i = 0; i < 8; ++i) {
        const int mrow = m0 + wm + i * 16 + quad * 4;
        #pragma unroll
        for (int j = 0; j < 4; ++j) {
            const int ncol = n0 + wn + j * 16 + l15;
            float* op = out + (size_t)mrow * N_DIM + ncol;
            #pragma unroll
            for (int r = 0; r < 4; ++r)
                op[(size_t)r * N_DIM] = acc[i][j][r];
        }
    }
}

// ================= fallback (no workspace): verified 128x128 kernel =================
__global__ __launch_bounds__(256, 2)
void gptq_gemm_f32(const float* __restrict__ x, const int* __restrict__ qw,
                   const float* __restrict__ sc, const int* __restrict__ qz,
                   float* __restrict__ out)
{
    constexpr int AK = 40;
    __shared__ __align__(16) f16 As[128 * AK];
    __shared__ __align__(16) f16 Bs[128 * 40];

    const int tid  = threadIdx.x;
    const int lane = tid & 63;
    const int wave = tid >> 6;
    const int quad = lane >> 4;
    const int l15  = lane & 15;
    const int wm   = (wave & 1) * 64;
    const int wn   = (wave >> 1) * 64;
    const int m0 = blockIdx.y * 128;
    const int n0 = blockIdx.x * 128;

    const float* agf = x + (size_t)(m0 + (tid >> 1)) * K_DIM + (tid & 1) * 16;
    f16* alf = As + (tid >> 1) * AK + (tid & 1) * 16;

    const int dn  = tid & 127;
    const int dkq = tid >> 7;
    const int gn  = n0 + dn;
    const int zsh = (gn & 7) * 4;
    const int*   qwp = qw + gn;
    const int*   qzp = qz + (gn >> 3);
    const float* scp = sc + gn;
    f16* bs0 = Bs + dn * 40 + dkq * 8;

    f32x4 acc[4][4];
    #pragma unroll
    for (int i = 0; i < 4; i++)
        #pragma unroll
        for (int j = 0; j < 4; j++)
            acc[i][j] = (f32x4){0.f, 0.f, 0.f, 0.f};

    for (int g = 0; g < K_DIM / 128; g++) {
        const u32 zq = (u32)qzp[(size_t)g * NQ8];
        const int z1 = (int)((zq >> zsh) & 15u) + 1;
        const float s = scp[(size_t)g * N_DIM];
        const f16 sh = (f16)s;
        const f16 bh = (f16)(-(float)(1024 + z1));
        const f16x2 s2 = {sh, sh}, b2 = {bh, bh};

        #pragma unroll
        for (int t = 0; t < 4; t++) {
            const int kt = g * 4 + t;
            uint4 bv[2];
            #pragma unroll
            for (int i = 0; i < 2; i++)
                bv[i] = dq8((u32)qwp[(size_t)(4 * kt + dkq + 2 * i) * N_DIM], b2, s2);

            const float4* agp = (const float4*)(agf + kt * 32);
            float4 a0 = agp[0], a1 = agp[1], a2 = agp[2], a3 = agp[3];
            uint4 av0, av1;
            av0.x = pk2(a0.x, a1.x); av0.y = pk2(a0.y, a1.y);
            av0.z = pk2(a0.z, a1.z); av0.w = pk2(a0.w, a1.w);
            av1.x = pk2(a2.x, a3.x); av1.y = pk2(a2.y, a3.y);
            av1.z = pk2(a2.z, a3.z); av1.w = pk2(a2.w, a3.w);
            *(uint4*)(alf)     = av0;
            *(uint4*)(alf + 8) = av1;
            *(uint4*)(bs0)      = bv[0];
            *(uint4*)(bs0 + 16) = bv[1];
            __syncthreads();

            f16x8 af[4], bfr[4];
            #pragma unroll
            for (int t2 = 0; t2 < 4; t2++) {
                af[t2]  = *(const f16x8*)(As + (wm + t2 * 16 + l15) * AK + quad * 8);
                bfr[t2] = *(const f16x8*)(Bs + (wn + t2 * 16 + l15) * 40 + quad * 8);
            }
            #pragma unroll
            for (int i = 0; i < 4; i++)
                #pragma unroll
                for (int j = 0; j < 4; j++)
                    acc[i][j] = __builtin_amdgcn_mfma_f32_16x16x32_f16(af[i], bfr[j], acc[i][j], 0, 0, 0);
            __syncthreads();
        }
    }

    #pragma unroll
    for (int i = 0; i < 4; i++) {
        const int mrow = m0 + wm + i * 16 + quad * 4;
        #pragma unroll
        for (int j = 0; j < 4; j++) {
            const int ncol = n0 + wn + j * 16 + l15;
            float* op = out + (size_t)mrow * N_DIM + ncol;
            #pragma unroll
            for (int r = 0; r < 4; r++)
                op[(size_t)r * N_DIM] = acc[i][j][r];
        }
    }
}

extern "C" void kernel_launch(void* const* d_in, const int* in_sizes, int n_in,
                              void* d_out, int out_size, void* d_ws, size_t ws_size,
                              hipStream_t stream) {
    const float* x  = (const float*)d_in[0];
    const int*   qw = (const int*)d_in[1];
    const float* sc = (const float*)d_in[2];
    const int*   qz = (const int*)d_in[3];
    float* out = (float*)d_out;
    f16*   xh  = (f16*)d_ws;

    const bool pre = ws_size >= (size_t)M_DIM * K_DIM * sizeof(f16);  // 32 MB
    if (pre) {
        cvt_x<<<(M_DIM * K_DIM / 8) / 256, 256, 0, stream>>>(x, xh);
        gptq_gemm_big<<<dim3(N_DIM / BN, M_DIM / BM), 512, 0, stream>>>(xh, qw, sc, qz, out);
    } else {
        gptq_gemm_f32<<<dim3(N_DIM / 128, M_DIM / 128), 256, 0, stream>>>(x, qw, sc, qz, out);
    }
}

// Round 4
// 602.521 us; speedup vs baseline: 1.1649x; 1.1649x over previous
//
#include <hip/hip_runtime.h>

typedef unsigned short u16;
typedef unsigned int   u32;
typedef _Float16       f16;

#define M_DIM 4096
#define K_DIM 4096
#define N_DIM 11008
#define NQ8   (N_DIM / 8)

typedef f16   f16x8 __attribute__((ext_vector_type(8)));
typedef f16   f16x2 __attribute__((ext_vector_type(2)));
typedef float f32x4 __attribute__((ext_vector_type(4)));
typedef u32   u32x4 __attribute__((ext_vector_type(4)));
typedef float f32x4v __attribute__((ext_vector_type(4)));

typedef __attribute__((address_space(1))) void GV;
typedef __attribute__((address_space(3))) void LV;
typedef __attribute__((address_space(3))) f16   lf16;
typedef __attribute__((address_space(3))) f16x8 lf16x8;
typedef __attribute__((address_space(3))) u32x4 lu32x4;

#define BAR()    __builtin_amdgcn_s_barrier()
#define WAITV(N) asm volatile("s_waitcnt vmcnt(" #N ")" ::: "memory")
#define WAITL0() asm volatile("s_waitcnt lgkmcnt(0)" ::: "memory")

__device__ __forceinline__ u32 pk2(float lo, float hi) {
    // v_cvt_pkrtz_f16_f32; exact for fp16-representable values (x is fp16-origin).
    return __builtin_bit_cast(u32, __builtin_amdgcn_cvt_pkrtz(lo, hi));
}

// x -> fp16 with per-8-group k-permutation: pairs (k0,k4),(k1,k5),(k2,k6),(k3,k7),
// matching the B-side nibble pairing ((q>>4j) gives nibbles j and j+4 in one mask).
__global__ __launch_bounds__(256) void cvt_x(const float* __restrict__ x, f16* __restrict__ xh) {
    const size_t t = (size_t)blockIdx.x * 256 + threadIdx.x;  // one 8-group per thread
    const float4* p = (const float4*)(x + t * 8);
    float4 a0 = p[0], a1 = p[1];
    u32x4 v;
    v.x = pk2(a0.x, a1.x); v.y = pk2(a0.y, a1.y);
    v.z = pk2(a0.z, a1.z); v.w = pk2(a0.w, a1.w);
    *(u32x4*)(xh + t * 8) = v;
}

// Dequant one qweight dword -> 8 fp16 (pair order), b2 = -(1025+z) exact, s2 = scale.
// ((q>>4j)&0x000F000F)|0x64006400 = fp16x2(1024+wj, 1024+w(j+4)) exact;
// pk_add exact integer bias; pk_mul = single fp16 rounding (= reference).
__device__ __forceinline__ u32x4 dq8(u32 q, f16x2 b2, f16x2 s2) {
    u32 pk[4];
    #pragma unroll
    for (int j = 0; j < 4; j++) {
        const u32 mb = ((q >> (4 * j)) & 0x000F000Fu) | 0x64006400u;
        f16x2 v2 = __builtin_bit_cast(f16x2, mb);
        f16x2 w2 = (v2 + b2) * s2;
        pk[j] = __builtin_bit_cast(u32, w2);
    }
    u32x4 r; r.x = pk[0]; r.y = pk[1]; r.z = pk[2]; r.w = pk[3];
    return r;
}

// ================= 256x256, BK=64, 2-K-tile/iter 8-phase (m201 clone) =================
#define BM 256
#define BN 256
#define BK 64

// af <- A frags (4 m-frags x 2 k-slots) from buf BUF, m-half MH. All offsets immediate.
#define LDA(MH, BUF) do { \
    _Pragma("unroll") for (int mf = 0; mf < 4; ++mf) { \
        af[mf][0] = *(const lf16x8*)(pAr0 + (BUF)*16384 + (MH)*4096 + mf*1024); \
        af[mf][1] = *(const lf16x8*)(pAr1 + (BUF)*16384 + (MH)*4096 + mf*1024); \
    } } while (0)

// BF <- B frags (2 n-frags x 2 k-slots) from buf BUF, n-half NH.
#define LDB(BF, NH, BUF) do { \
    _Pragma("unroll") for (int nf = 0; nf < 2; ++nf) { \
        BF[nf][0] = *(const lf16x8*)(pBr0 + (BUF)*16384 + (NH)*2048 + nf*1024); \
        BF[nf][1] = *(const lf16x8*)(pBr1 + (BUF)*16384 + (NH)*2048 + nf*1024); \
    } } while (0)

#define STAGE_A(J, BUF, PTR) __builtin_amdgcn_global_load_lds( \
    (GV*)(PTR), (LV*)(&As[0][0] + (BUF)*16384 + (tid + (J)*512)*8), 16, 0, 0)

#define STAGE_B(R, BUF, BQ, B2, S2) \
    *(lu32x4*)(pBw + (BUF)*16384 + bwo[R]) = dq8((BQ)[R], (B2), (S2))

#define MFMA16(AI, BF, CJ) do { \
    _Pragma("unroll") for (int ks = 0; ks < 2; ++ks) \
    _Pragma("unroll") for (int mf = 0; mf < 4; ++mf) \
    _Pragma("unroll") for (int nf = 0; nf < 2; ++nf) \
        acc[(AI)+mf][(CJ)+nf] = __builtin_amdgcn_mfma_f32_16x16x32_f16( \
            af[mf][ks], (BF)[nf][ks], acc[(AI)+mf][(CJ)+nf], 0, 0, 0); \
    } while (0)

#define PRIO1() __builtin_amdgcn_s_setprio(1)
#define PRIO0() __builtin_amdgcn_s_setprio(0)

// LDS layout (A and B tiles): tile[row][chunk ^ (row&7)], chunk = 16B k-chunk (8/row).
// A: glds dest linear in tid order (wave-uniform + lane*16), source pre-inverse-swizzled.
// B: reg-dequant + swizzled ds_write_b128. Quarter-wave read patterns land 2-way (free).
__global__ __launch_bounds__(512, 2)
void gptq_gemm_big(const f16* __restrict__ xh, const int* __restrict__ qw,
                   const float* __restrict__ sc, const int* __restrict__ qz,
                   float* __restrict__ out)
{
    __shared__ __align__(16) f16 As[2][BM * BK];
    __shared__ __align__(16) f16 Bs[2][BN * BK];

    const int tid  = threadIdx.x;
    const int lane = tid & 63;
    const int wave = tid >> 6;
    const int quad = lane >> 4;
    const int l15  = lane & 15;
    const int sw   = l15 & 7;
    const int wm   = (wave >> 2) * 128;   // 2 waves in M
    const int wn   = (wave & 3) * 64;     // 4 waves in N

    // bijective XCD swizzle: 688 blocks = 8 * 86.
    const int bid0 = blockIdx.y * 43 + blockIdx.x;
    const int bid  = (bid0 & 7) * 86 + (bid0 >> 3);
    const int n0 = (bid % 43) * BN;
    const int m0 = (bid / 43) * BM;

    const int cko0 = (quad ^ sw) * 8;        // k-slot 0 chunk offset (halfs)
    const int cko1 = ((4 + quad) ^ sw) * 8;  // k-slot 1

    // LDS bases as explicit addrspace(3) pointers: guarantees ds_read/ds_write
    // (a flat op here would also count in vmcnt and corrupt the counted waits).
    const lf16* pAr0 = (const lf16*)&As[0][0] + (wm + l15) * 64 + cko0;
    const lf16* pAr1 = (const lf16*)&As[0][0] + (wm + l15) * 64 + cko1;
    const lf16* pBr0 = (const lf16*)&Bs[0][0] + (wn + l15) * 64 + cko0;
    const lf16* pBr1 = (const lf16*)&Bs[0][0] + (wn + l15) * 64 + cko1;
    lf16* pBw = (lf16*)&Bs[0][0];

    // ---- A staging: slot s=(tid+j*512) -> row s>>3, lds-chunk s&7;
    //      global chunk = (s&7)^(row&7) (invariant over j since j*64 ≡ 0 mod 8).
    const int arow = tid >> 3;
    const int acnk = (tid & 7) ^ (arow & 7);
    const f16* agp[4];
    #pragma unroll
    for (int j = 0; j < 4; ++j)
        agp[j] = xh + (size_t)(m0 + j * 64 + arow) * K_DIM + acnk * 8;

    // ---- B dequant geometry: thread owns column bn, qweight rows qr0..qr0+3 of each tile.
    const int bn   = tid >> 1;
    const int bsub = tid & 1;
    const int qr0  = bsub * 4;
    const int gn   = n0 + bn;
    const int zsh  = (gn & 7) * 4;
    const int*   qcol = qw + gn;
    const int*   qzp  = qz + (gn >> 3);
    const float* scp  = sc + gn;
    int bwo[4];
    #pragma unroll
    for (int i = 0; i < 4; ++i)
        bwo[i] = (bn * 8 + ((qr0 + i) ^ (bn & 7))) * 8;   // halfs

    f32x4 acc[8][4];
    #pragma unroll
    for (int i = 0; i < 8; ++i)
        #pragma unroll
        for (int j = 0; j < 4; ++j)
            acc[i][j] = (f32x4){0.f, 0.f, 0.f, 0.f};

    f16x8 af[4][2], bf0[2][2], bf1[2][2];
    u32 bqA[4], bqB[4];      // qweight dwords: bqA = odd tile (2i+1), bqB = even tile (2i+2)
    u32 zq_c; float sv_c;    // group params: current (group i), next (group i+1)
    u32 zq_n; float sv_n;

    // ================= prologue: stage tile 0 -> buf0; preload tile-1 params ========
    {
        zq_c = (u32)qzp[0];
        sv_c = scp[0];
        u32 bq0[4];
        #pragma unroll
        for (int j = 0; j < 4; ++j) bq0[j] = (u32)qcol[(size_t)(qr0 + j) * N_DIM];
        #pragma unroll
        for (int j = 0; j < 4; ++j) STAGE_A(j, 0, agp[j]);
        #pragma unroll
        for (int j = 0; j < 4; ++j) bqA[j] = (u32)qcol[(size_t)(8 + qr0 + j) * N_DIM];
        const f16 sh = (f16)sv_c;
        const f16 bh = (f16)(-(float)(1025 + (int)((zq_c >> zsh) & 15u)));
        const f16x2 s2 = {sh, sh}, b2 = {bh, bh};
        #pragma unroll
        for (int r = 0; r < 4; ++r) STAGE_B(r, 0, bq0, b2, s2);
        WAITV(0); WAITL0();
        BAR();
    }

    // ================= main loop: iter i computes tiles 2i (buf0), 2i+1 (buf1) ======
    #pragma unroll 1
    for (int i = 0; i < 32; ++i) {
        const f16 shc = (f16)sv_c;
        const f16 bhc = (f16)(-(float)(1025 + (int)((zq_c >> zsh) & 15u)));
        const f16x2 s2c = {shc, shc}, b2c = {bhc, bhc};
        const int t2 = (i < 31) ? 2 * i + 2 : 63;     // clamp keeps addresses in-bounds
        const int t3 = (i < 31) ? 2 * i + 3 : 63;
        const int gnx = (i < 31) ? i + 1 : 31;
        const int a5off = (i < 31) ? 128 : 64;        // halfs: tile 2i+2 (or re-stage 2i+1)

        // ---------- P1: read buf0(mh0,nh0); stage buf1 Ah0 (tile 2i+1); B loads ----------
        LDA(0, 0);
        LDB(bf0, 0, 0);
        STAGE_A(0, 1, agp[0] + 64);
        STAGE_A(2, 1, agp[2] + 64);
        #pragma unroll
        for (int j = 0; j < 4; ++j) bqB[j] = (u32)qcol[(size_t)(t2 * 8 + qr0 + j) * N_DIM];
        zq_n = (u32)qzp[(size_t)gnx * NQ8];
        sv_n = scp[(size_t)gnx * N_DIM];
        STAGE_B(0, 1, bqA, b2c, s2c);
        BAR(); PRIO1(); MFMA16(0, bf0, 0); PRIO0(); BAR();

        // ---------- P2: read buf0(nh1); stage buf1 Ah1 ----------
        LDB(bf1, 1, 0);
        STAGE_A(1, 1, agp[1] + 64);
        STAGE_A(3, 1, agp[3] + 64);
        STAGE_B(1, 1, bqA, b2c, s2c);
        BAR(); PRIO1(); MFMA16(0, bf1, 2); PRIO0(); WAITV(10); BAR();

        // ---------- P3: read buf0(mh1) ----------
        LDA(1, 0);
        STAGE_B(2, 1, bqA, b2c, s2c);
        BAR(); PRIO1(); MFMA16(4, bf1, 2); PRIO0(); BAR();

        // ---------- P4: flush buf1 writes; force buf1 Ah0 landed ----------
        STAGE_B(3, 1, bqA, b2c, s2c);
        BAR(); PRIO1(); MFMA16(4, bf0, 0); PRIO0(); WAITV(2); WAITL0(); BAR();

        // ======== second K-tile: compute buf1 (tile 2i+1), stage buf0 (tile 2i+2) ========
        const f16 shn = (f16)sv_n;
        const f16 bhn = (f16)(-(float)(1025 + (int)((zq_n >> zsh) & 15u)));
        const f16x2 s2n = {shn, shn}, b2n = {bhn, bhn};

        // ---------- P5 ----------
        LDA(0, 1);
        LDB(bf0, 0, 1);
        STAGE_A(0, 0, agp[0] + a5off);
        STAGE_A(2, 0, agp[2] + a5off);
        #pragma unroll
        for (int j = 0; j < 4; ++j) bqA[j] = (u32)qcol[(size_t)(t3 * 8 + qr0 + j) * N_DIM];
        STAGE_B(0, 0, bqB, b2n, s2n);
        BAR(); PRIO1(); MFMA16(0, bf0, 0); PRIO0(); BAR();

        // ---------- P6 ----------
        LDB(bf1, 1, 1);
        STAGE_A(1, 0, agp[1] + a5off);
        STAGE_A(3, 0, agp[3] + a5off);
        STAGE_B(1, 0, bqB, b2n, s2n);
        BAR(); PRIO1(); MFMA16(0, bf1, 2); PRIO0(); WAITV(8); BAR();

        // ---------- P7 ----------
        LDA(1, 1);
        STAGE_B(2, 0, bqB, b2n, s2n);
        BAR(); PRIO1(); MFMA16(4, bf1, 2); PRIO0(); BAR();

        // ---------- P8 ----------
        STAGE_B(3, 0, bqB, b2n, s2n);
        BAR(); PRIO1(); MFMA16(4, bf0, 0); PRIO0(); WAITV(2); WAITL0(); BAR();

        zq_c = zq_n; sv_c = sv_n;
        #pragma unroll
        for (int j = 0; j < 4; ++j) agp[j] += 128;    // advance 2 tiles (256B)
    }

    // Drain: 2 glds are still in flight by design; an LDS-writing load left
    // outstanding past s_endpgm can scribble into a re-allocated LDS block.
    WAITV(0); WAITL0();

    // epilogue: C/D layout col=lane&15, row=quad*4+r
    #pragma unroll
    for (int i = 0; i < 8; ++i) {
        const int mrow = m0 + wm + i * 16 + quad * 4;
        #pragma unroll
        for (int j = 0; j < 4; ++j) {
            const int ncol = n0 + wn + j * 16 + l15;
            float* op = out + (size_t)mrow * N_DIM + ncol;
            #pragma unroll
            for (int r = 0; r < 4; ++r)
                op[(size_t)r * N_DIM] = acc[i][j][r];
        }
    }
}

// ================= fallback (no workspace): verified 128x128 kernel =================
__global__ __launch_bounds__(256, 2)
void gptq_gemm_f32(const float* __restrict__ x, const int* __restrict__ qw,
                   const float* __restrict__ sc, const int* __restrict__ qz,
                   float* __restrict__ out)
{
    constexpr int AK = 40;
    __shared__ __align__(16) f16 As[128 * AK];
    __shared__ __align__(16) f16 Bs[128 * 40];

    const int tid  = threadIdx.x;
    const int lane = tid & 63;
    const int wave = tid >> 6;
    const int quad = lane >> 4;
    const int l15  = lane & 15;
    const int wm   = (wave & 1) * 64;
    const int wn   = (wave >> 1) * 64;
    const int m0 = blockIdx.y * 128;
    const int n0 = blockIdx.x * 128;

    const float* agf = x + (size_t)(m0 + (tid >> 1)) * K_DIM + (tid & 1) * 16;
    f16* alf = As + (tid >> 1) * AK + (tid & 1) * 16;

    const int dn  = tid & 127;
    const int dkq = tid >> 7;
    const int gn  = n0 + dn;
    const int zsh = (gn & 7) * 4;
    const int*   qwp = qw + gn;
    const int*   qzp = qz + (gn >> 3);
    const float* scp = sc + gn;
    f16* bs0 = Bs + dn * 40 + dkq * 8;

    f32x4 acc[4][4];
    #pragma unroll
    for (int i = 0; i < 4; i++)
        #pragma unroll
        for (int j = 0; j < 4; j++)
            acc[i][j] = (f32x4){0.f, 0.f, 0.f, 0.f};

    for (int g = 0; g < K_DIM / 128; g++) {
        const u32 zq = (u32)qzp[(size_t)g * NQ8];
        const int z1 = (int)((zq >> zsh) & 15u) + 1;
        const float s = scp[(size_t)g * N_DIM];
        const f16 sh = (f16)s;
        const f16 bh = (f16)(-(float)(1024 + z1));
        const f16x2 s2 = {sh, sh}, b2 = {bh, bh};

        #pragma unroll
        for (int t = 0; t < 4; t++) {
            const int kt = g * 4 + t;
            u32x4 bv[2];
            #pragma unroll
            for (int i = 0; i < 2; i++)
                bv[i] = dq8((u32)qwp[(size_t)(4 * kt + dkq + 2 * i) * N_DIM], b2, s2);

            const float4* agp2 = (const float4*)(agf + kt * 32);
            float4 a0 = agp2[0], a1 = agp2[1], a2 = agp2[2], a3 = agp2[3];
            u32x4 av0, av1;
            av0.x = pk2(a0.x, a1.x); av0.y = pk2(a0.y, a1.y);
            av0.z = pk2(a0.z, a1.z); av0.w = pk2(a0.w, a1.w);
            av1.x = pk2(a2.x, a3.x); av1.y = pk2(a2.y, a3.y);
            av1.z = pk2(a2.z, a3.z); av1.w = pk2(a2.w, a3.w);
            *(u32x4*)(alf)     = av0;
            *(u32x4*)(alf + 8) = av1;
            *(u32x4*)(bs0)      = bv[0];
            *(u32x4*)(bs0 + 16) = bv[1];
            __syncthreads();

            f16x8 af[4], bfr[4];
            #pragma unroll
            for (int t2 = 0; t2 < 4; t2++) {
                af[t2]  = *(const f16x8*)(As + (wm + t2 * 16 + l15) * AK + quad * 8);
                bfr[t2] = *(const f16x8*)(Bs + (wn + t2 * 16 + l15) * 40 + quad * 8);
            }
            #pragma unroll
            for (int i = 0; i < 4; i++)
                #pragma unroll
                for (int j = 0; j < 4; j++)
                    acc[i][j] = __builtin_amdgcn_mfma_f32_16x16x32_f16(af[i], bfr[j], acc[i][j], 0, 0, 0);
            __syncthreads();
        }
    }

    #pragma unroll
    for (int i = 0; i < 4; i++) {
        const int mrow = m0 + wm + i * 16 + quad * 4;
        #pragma unroll
        for (int j = 0; j < 4; j++) {
            const int ncol = n0 + wn + j * 16 + l15;
            float* op = out + (size_t)mrow * N_DIM + ncol;
            #pragma unroll
            for (int r = 0; r < 4; r++)
                op[(size_t)r * N_DIM] = acc[i][j][r];
        }
    }
}

extern "C" void kernel_launch(void* const* d_in, const int* in_sizes, int n_in,
                              void* d_out, int out_size, void* d_ws, size_t ws_size,
                              hipStream_t stream) {
    const float* x  = (const float*)d_in[0];
    const int*   qw = (const int*)d_in[1];
    const float* sc = (const float*)d_in[2];
    const int*   qz = (const int*)d_in[3];
    float* out = (float*)d_out;
    f16*   xh  = (f16*)d_ws;

    const bool pre = ws_size >= (size_t)M_DIM * K_DIM * sizeof(f16);  // 32 MB
    if (pre) {
        cvt_x<<<(M_DIM * K_DIM / 8) / 256, 256, 0, stream>>>(x, xh);
        gptq_gemm_big<<<dim3(N_DIM / BN, M_DIM / BM), 512, 0, stream>>>(xh, qw, sc, qz, out);
    } else {
        gptq_gemm_f32<<<dim3(N_DIM / 128, M_DIM / 128), 256, 0, stream>>>(x, qw, sc, qz, out);
    }
}

// Round 5
// 575.314 us; speedup vs baseline: 1.2200x; 1.0473x over previous
//
#include <hip/hip_runtime.h>

typedef unsigned short u16;
typedef unsigned int   u32;
typedef _Float16       f16;

#define M_DIM 4096
#define K_DIM 4096
#define N_DIM 11008
#define NQ8   (N_DIM / 8)

typedef f16   f16x8 __attribute__((ext_vector_type(8)));
typedef f16   f16x2 __attribute__((ext_vector_type(2)));
typedef float f32x4 __attribute__((ext_vector_type(4)));
typedef u32   u32x4 __attribute__((ext_vector_type(4)));

typedef __attribute__((address_space(1))) void GV;
typedef __attribute__((address_space(3))) void LV;
typedef __attribute__((address_space(3))) f16   lf16;
typedef __attribute__((address_space(3))) f16x8 lf16x8;
typedef __attribute__((address_space(3))) u32x4 lu32x4;

#define BAR()    __builtin_amdgcn_s_barrier()
#define WAITV(N) asm volatile("s_waitcnt vmcnt(" #N ")" ::: "memory")
#define WAITL0() asm volatile("s_waitcnt lgkmcnt(0)" ::: "memory")

__device__ __forceinline__ u32 pk2(float lo, float hi) {
    // v_cvt_pkrtz_f16_f32; exact for fp16-representable values (x is fp16-origin).
    return __builtin_bit_cast(u32, __builtin_amdgcn_cvt_pkrtz(lo, hi));
}

// x -> fp16 with per-8-group k-permutation: pairs (k0,k4),(k1,k5),(k2,k6),(k3,k7),
// matching the B-side nibble pairing ((q>>4j) gives nibbles j and j+4 in one mask).
__global__ __launch_bounds__(256) void cvt_x(const float* __restrict__ x, f16* __restrict__ xh) {
    const size_t t = (size_t)blockIdx.x * 256 + threadIdx.x;  // one 8-group per thread
    const float4* p = (const float4*)(x + t * 8);
    float4 a0 = p[0], a1 = p[1];
    u32x4 v;
    v.x = pk2(a0.x, a1.x); v.y = pk2(a0.y, a1.y);
    v.z = pk2(a0.z, a1.z); v.w = pk2(a0.w, a1.w);
    *(u32x4*)(xh + t * 8) = v;
}

// Dequant one qweight dword -> 8 fp16 (pair order), b2 = -(1025+z) exact, s2 = scale.
// ((q>>4j)&0x000F000F)|0x64006400 = fp16x2(1024+wj, 1024+w(j+4)) exact;
// pk_add exact integer bias; pk_mul = single fp16 rounding (= reference).
__device__ __forceinline__ u32x4 dq8(u32 q, f16x2 b2, f16x2 s2) {
    u32 pk[4];
    #pragma unroll
    for (int j = 0; j < 4; j++) {
        const u32 mb = ((q >> (4 * j)) & 0x000F000Fu) | 0x64006400u;
        f16x2 v2 = __builtin_bit_cast(f16x2, mb);
        f16x2 w2 = (v2 + b2) * s2;
        pk[j] = __builtin_bit_cast(u32, w2);
    }
    u32x4 r; r.x = pk[0]; r.y = pk[1]; r.z = pk[2]; r.w = pk[3];
    return r;
}

// ============ 256x256, BK=64; 5-barrier K-tile, reads/dequant folded into MFMA regions ====
#define BM 256
#define BN 256
#define BK 64

// af <- A frags (4 m-frags x 2 k-slots) from buf BUF, m-half MH. All offsets immediate.
#define LDA(MH, BUF) do { \
    _Pragma("unroll") for (int mf = 0; mf < 4; ++mf) { \
        af[mf][0] = *(const lf16x8*)(pAr0 + (BUF)*16384 + (MH)*4096 + mf*1024); \
        af[mf][1] = *(const lf16x8*)(pAr1 + (BUF)*16384 + (MH)*4096 + mf*1024); \
    } } while (0)

// BF <- B frags (2 n-frags x 2 k-slots) from buf BUF, n-half NH.
#define LDB(BF, NH, BUF) do { \
    _Pragma("unroll") for (int nf = 0; nf < 2; ++nf) { \
        BF[nf][0] = *(const lf16x8*)(pBr0 + (BUF)*16384 + (NH)*2048 + nf*1024); \
        BF[nf][1] = *(const lf16x8*)(pBr1 + (BUF)*16384 + (NH)*2048 + nf*1024); \
    } } while (0)

#define STAGE_A(J, BUF, PTR) __builtin_amdgcn_global_load_lds( \
    (GV*)(PTR), (LV*)(&As[0][0] + (BUF)*16384 + (tid + (J)*512)*8), 16, 0, 0)

#define STAGE_B(R, BUF, BQ, B2, S2) \
    *(lu32x4*)(pBw + (BUF)*16384 + bwo[R]) = dq8((BQ)[R], (B2), (S2))

#define MFMA16(AI, BF, CJ) do { \
    _Pragma("unroll") for (int ks = 0; ks < 2; ++ks) \
    _Pragma("unroll") for (int mf = 0; mf < 4; ++mf) \
    _Pragma("unroll") for (int nf = 0; nf < 2; ++nf) \
        acc[(AI)+mf][(CJ)+nf] = __builtin_amdgcn_mfma_f32_16x16x32_f16( \
            af[mf][ks], (BF)[nf][ks], acc[(AI)+mf][(CJ)+nf], 0, 0, 0); \
    } while (0)

#define PRIO1() __builtin_amdgcn_s_setprio(1)
#define PRIO0() __builtin_amdgcn_s_setprio(0)

// LDS layout (A and B tiles): tile[row][chunk ^ (row&7)], chunk = 16B k-chunk (8/row).
// A: glds dest linear in tid order (wave-uniform + lane*16), source pre-inverse-swizzled.
// B: reg-dequant + swizzled ds_write_b128. Quarter-wave read patterns land 2-way (free).
//
// K-tile schedule (5 barriers; serial windows hold only issue, no dependent VALU):
//   entry: LDA(mh0) LDB(bf0) + 4 glds -> BAR
//   Q1: MFMA(mh0,bf0) | LDB(bf1) | qw/param loads | dq8+write d0 -> BAR
//   Q2: MFMA(mh0,bf1) | LDA(mh1, WAR-reuse af)    | dq8+write d1 -> BAR
//   Q3: MFMA(mh1,bf1)                             | dq8+write d2 -> BAR
//   Q4: MFMA(mh1,bf0)                             | dq8+write d3 -> WAITV WAITL0 BAR
// vmcnt ledger: per tile issue = [4 glds][4 qw (+2 param on even tiles)].
//   even-tile exit WAITV(6): outstanding 10 -> retire the 4 glds, keep qw+param.
//   odd-tile  exit WAITV(4): outstanding  8 -> retire the 4 glds, keep 4 qw.
__global__ __launch_bounds__(512, 2)
void gptq_gemm_big(const f16* __restrict__ xh, const int* __restrict__ qw,
                   const float* __restrict__ sc, const int* __restrict__ qz,
                   float* __restrict__ out)
{
    __shared__ __align__(16) f16 As[2][BM * BK];
    __shared__ __align__(16) f16 Bs[2][BN * BK];

    const int tid  = threadIdx.x;
    const int lane = tid & 63;
    const int wave = tid >> 6;
    const int quad = lane >> 4;
    const int l15  = lane & 15;
    const int sw   = l15 & 7;
    const int wm   = (wave >> 2) * 128;   // 2 waves in M
    const int wn   = (wave & 3) * 64;     // 4 waves in N

    // bijective XCD swizzle: 688 blocks = 8 * 86.
    const int bid0 = blockIdx.y * 43 + blockIdx.x;
    const int bid  = (bid0 & 7) * 86 + (bid0 >> 3);
    const int n0 = (bid % 43) * BN;
    const int m0 = (bid / 43) * BM;

    const int cko0 = (quad ^ sw) * 8;        // k-slot 0 chunk offset (halfs)
    const int cko1 = ((4 + quad) ^ sw) * 8;  // k-slot 1

    // LDS bases as explicit addrspace(3) pointers: guarantees ds_read/ds_write
    // (a flat op here would also count in vmcnt and corrupt the counted waits).
    const lf16* pAr0 = (const lf16*)&As[0][0] + (wm + l15) * 64 + cko0;
    const lf16* pAr1 = (const lf16*)&As[0][0] + (wm + l15) * 64 + cko1;
    const lf16* pBr0 = (const lf16*)&Bs[0][0] + (wn + l15) * 64 + cko0;
    const lf16* pBr1 = (const lf16*)&Bs[0][0] + (wn + l15) * 64 + cko1;
    lf16* pBw = (lf16*)&Bs[0][0];

    // ---- A staging: slot s=(tid+j*512) -> row s>>3, lds-chunk s&7;
    //      global chunk = (s&7)^(row&7) (invariant over j since j*64 ≡ 0 mod 8).
    const int arow = tid >> 3;
    const int acnk = (tid & 7) ^ (arow & 7);
    const f16* agp[4];
    #pragma unroll
    for (int j = 0; j < 4; ++j)
        agp[j] = xh + (size_t)(m0 + j * 64 + arow) * K_DIM + acnk * 8;

    // ---- B dequant geometry: thread owns column bn, qweight rows qr0..qr0+3 of each tile.
    const int bn   = tid >> 1;
    const int bsub = tid & 1;
    const int qr0  = bsub * 4;
    const int gn   = n0 + bn;
    const int zsh  = (gn & 7) * 4;
    const int*   qcol = qw + gn;
    const int*   qzp  = qz + (gn >> 3);
    const float* scp  = sc + gn;
    int bwo[4];
    #pragma unroll
    for (int i = 0; i < 4; ++i)
        bwo[i] = (bn * 8 + ((qr0 + i) ^ (bn & 7))) * 8;   // halfs

    f32x4 acc[8][4];
    #pragma unroll
    for (int i = 0; i < 8; ++i)
        #pragma unroll
        for (int j = 0; j < 4; ++j)
            acc[i][j] = (f32x4){0.f, 0.f, 0.f, 0.f};

    f16x8 af[4][2], bf0[2][2], bf1[2][2];
    u32 bqA[4], bqB[4];      // qweight dwords: bqA = odd tile (2i+1), bqB = even tile (2i+2)
    u32 zq_c; float sv_c;    // group params: current (group i), next (group i+1)
    u32 zq_n; float sv_n;

    // ================= prologue: stage tile 0 -> buf0; preload tile-1 qw ========
    {
        zq_c = (u32)qzp[0];
        sv_c = scp[0];
        u32 bq0[4];
        #pragma unroll
        for (int j = 0; j < 4; ++j) bq0[j] = (u32)qcol[(size_t)(qr0 + j) * N_DIM];
        #pragma unroll
        for (int j = 0; j < 4; ++j) STAGE_A(j, 0, agp[j]);
        #pragma unroll
        for (int j = 0; j < 4; ++j) bqA[j] = (u32)qcol[(size_t)(8 + qr0 + j) * N_DIM];
        const f16 sh = (f16)sv_c;
        const f16 bh = (f16)(-(float)(1025 + (int)((zq_c >> zsh) & 15u)));
        const f16x2 s2 = {sh, sh}, b2 = {bh, bh};
        #pragma unroll
        for (int r = 0; r < 4; ++r) STAGE_B(r, 0, bq0, b2, s2);
        WAITV(0); WAITL0();
        BAR();
    }

    // ================= main loop: iter i computes tiles 2i (buf0), 2i+1 (buf1) ======
    #pragma unroll 1
    for (int i = 0; i < 32; ++i) {
        const f16 shc = (f16)sv_c;
        const f16 bhc = (f16)(-(float)(1025 + (int)((zq_c >> zsh) & 15u)));
        const f16x2 s2c = {shc, shc}, b2c = {bhc, bhc};
        const int t2 = (i < 31) ? 2 * i + 2 : 63;     // clamp keeps addresses in-bounds
        const int t3 = (i < 31) ? 2 * i + 3 : 63;
        const int gnx = (i < 31) ? i + 1 : 31;
        const int a5off = (i < 31) ? 128 : 64;        // halfs: tile 2i+2 (or re-stage 2i+1)

        // ======== tile 2i: compute buf0, stage buf1 (tile 2i+1) ========
        // entry window: reads for Q1 + all 4 A-glds. Nothing else.
        LDA(0, 0);
        LDB(bf0, 0, 0);
        STAGE_A(0, 1, agp[0] + 64);
        STAGE_A(1, 1, agp[1] + 64);
        STAGE_A(2, 1, agp[2] + 64);
        STAGE_A(3, 1, agp[3] + 64);
        BAR();
        // Q1: MFMA | bf1 read-ahead | next-tile qw+param loads | d0
        PRIO1(); MFMA16(0, bf0, 0); PRIO0();
        LDB(bf1, 1, 0);
        #pragma unroll
        for (int j = 0; j < 4; ++j) bqB[j] = (u32)qcol[(size_t)(t2 * 8 + qr0 + j) * N_DIM];
        zq_n = (u32)qzp[(size_t)gnx * NQ8];
        sv_n = scp[(size_t)gnx * N_DIM];
        STAGE_B(0, 1, bqA, b2c, s2c);
        BAR();
        // Q2: MFMA | af mh1 read-ahead (WAR reuse of af regs) | d1
        PRIO1(); MFMA16(0, bf1, 2); PRIO0();
        LDA(1, 0);
        STAGE_B(1, 1, bqA, b2c, s2c);
        BAR();
        // Q3: MFMA | d2
        PRIO1(); MFMA16(4, bf1, 2); PRIO0();
        STAGE_B(2, 1, bqA, b2c, s2c);
        BAR();
        // Q4: MFMA | d3 | counted exit drain
        PRIO1(); MFMA16(4, bf0, 0); PRIO0();
        STAGE_B(3, 1, bqA, b2c, s2c);
        WAITV(6); WAITL0();
        BAR();

        // ======== tile 2i+1: compute buf1, stage buf0 (tile 2i+2) ========
        const f16 shn = (f16)sv_n;
        const f16 bhn = (f16)(-(float)(1025 + (int)((zq_n >> zsh) & 15u)));
        const f16x2 s2n = {shn, shn}, b2n = {bhn, bhn};

        LDA(0, 1);
        LDB(bf0, 0, 1);
        STAGE_A(0, 0, agp[0] + a5off);
        STAGE_A(1, 0, agp[1] + a5off);
        STAGE_A(2, 0, agp[2] + a5off);
        STAGE_A(3, 0, agp[3] + a5off);
        BAR();
        PRIO1(); MFMA16(0, bf0, 0); PRIO0();
        LDB(bf1, 1, 1);
        #pragma unroll
        for (int j = 0; j < 4; ++j) bqA[j] = (u32)qcol[(size_t)(t3 * 8 + qr0 + j) * N_DIM];
        STAGE_B(0, 0, bqB, b2n, s2n);
        BAR();
        PRIO1(); MFMA16(0, bf1, 2); PRIO0();
        LDA(1, 1);
        STAGE_B(1, 0, bqB, b2n, s2n);
        BAR();
        PRIO1(); MFMA16(4, bf1, 2); PRIO0();
        STAGE_B(2, 0, bqB, b2n, s2n);
        BAR();
        PRIO1(); MFMA16(4, bf0, 0); PRIO0();
        STAGE_B(3, 0, bqB, b2n, s2n);
        WAITV(4); WAITL0();
        BAR();

        zq_c = zq_n; sv_c = sv_n;
        #pragma unroll
        for (int j = 0; j < 4; ++j) agp[j] += 128;    // advance 2 tiles (256B)
    }

    // Drain: glds/qw loads may still be in flight; an LDS-writing load left
    // outstanding past s_endpgm can scribble into a re-allocated LDS block.
    WAITV(0); WAITL0();

    // epilogue: C/D layout col=lane&15, row=quad*4+r
    #pragma unroll
    for (int i = 0; i < 8; ++i) {
        const int mrow = m0 + wm + i * 16 + quad * 4;
        #pragma unroll
        for (int j = 0; j < 4; ++j) {
            const int ncol = n0 + wn + j * 16 + l15;
            float* op = out + (size_t)mrow * N_DIM + ncol;
            #pragma unroll
            for (int r = 0; r < 4; ++r)
                op[(size_t)r * N_DIM] = acc[i][j][r];
        }
    }
}

// ================= fallback (no workspace): verified 128x128 kernel =================
__global__ __launch_bounds__(256, 2)
void gptq_gemm_f32(const float* __restrict__ x, const int* __restrict__ qw,
                   const float* __restrict__ sc, const int* __restrict__ qz,
                   float* __restrict__ out)
{
    constexpr int AK = 40;
    __shared__ __align__(16) f16 As[128 * AK];
    __shared__ __align__(16) f16 Bs[128 * 40];

    const int tid  = threadIdx.x;
    const int lane = tid & 63;
    const int wave = tid >> 6;
    const int quad = lane >> 4;
    const int l15  = lane & 15;
    const int wm   = (wave & 1) * 64;
    const int wn   = (wave >> 1) * 64;
    const int m0 = blockIdx.y * 128;
    const int n0 = blockIdx.x * 128;

    const float* agf = x + (size_t)(m0 + (tid >> 1)) * K_DIM + (tid & 1) * 16;
    f16* alf = As + (tid >> 1) * AK + (tid & 1) * 16;

    const int dn  = tid & 127;
    const int dkq = tid >> 7;
    const int gn  = n0 + dn;
    const int zsh = (gn & 7) * 4;
    const int*   qwp = qw + gn;
    const int*   qzp = qz + (gn >> 3);
    const float* scp = sc + gn;
    f16* bs0 = Bs + dn * 40 + dkq * 8;

    f32x4 acc[4][4];
    #pragma unroll
    for (int i = 0; i < 4; i++)
        #pragma unroll
        for (int j = 0; j < 4; j++)
            acc[i][j] = (f32x4){0.f, 0.f, 0.f, 0.f};

    for (int g = 0; g < K_DIM / 128; g++) {
        const u32 zq = (u32)qzp[(size_t)g * NQ8];
        const int z1 = (int)((zq >> zsh) & 15u) + 1;
        const float s = scp[(size_t)g * N_DIM];
        const f16 sh = (f16)s;
        const f16 bh = (f16)(-(float)(1024 + z1));
        const f16x2 s2 = {sh, sh}, b2 = {bh, bh};

        #pragma unroll
        for (int t = 0; t < 4; t++) {
            const int kt = g * 4 + t;
            u32x4 bv[2];
            #pragma unroll
            for (int i = 0; i < 2; i++)
                bv[i] = dq8((u32)qwp[(size_t)(4 * kt + dkq + 2 * i) * N_DIM], b2, s2);

            const float4* agp2 = (const float4*)(agf + kt * 32);
            float4 a0 = agp2[0], a1 = agp2[1], a2 = agp2[2], a3 = agp2[3];
            u32x4 av0, av1;
            av0.x = pk2(a0.x, a1.x); av0.y = pk2(a0.y, a1.y);
            av0.z = pk2(a0.z, a1.z); av0.w = pk2(a0.w, a1.w);
            av1.x = pk2(a2.x, a3.x); av1.y = pk2(a2.y, a3.y);
            av1.z = pk2(a2.z, a3.z); av1.w = pk2(a2.w, a3.w);
            *(u32x4*)(alf)     = av0;
            *(u32x4*)(alf + 8) = av1;
            *(u32x4*)(bs0)      = bv[0];
            *(u32x4*)(bs0 + 16) = bv[1];
            __syncthreads();

            f16x8 af[4], bfr[4];
            #pragma unroll
            for (int t2 = 0; t2 < 4; t2++) {
                af[t2]  = *(const f16x8*)(As + (wm + t2 * 16 + l15) * AK + quad * 8);
                bfr[t2] = *(const f16x8*)(Bs + (wn + t2 * 16 + l15) * 40 + quad * 8);
            }
            #pragma unroll
            for (int i = 0; i < 4; i++)
                #pragma unroll
                for (int j = 0; j < 4; j++)
                    acc[i][j] = __builtin_amdgcn_mfma_f32_16x16x32_f16(af[i], bfr[j], acc[i][j], 0, 0, 0);
            __syncthreads();
        }
    }

    #pragma unroll
    for (int i = 0; i < 4; i++) {
        const int mrow = m0 + wm + i * 16 + quad * 4;
        #pragma unroll
        for (int j = 0; j < 4; j++) {
            const int ncol = n0 + wn + j * 16 + l15;
            float* op = out + (size_t)mrow * N_DIM + ncol;
            #pragma unroll
            for (int r = 0; r < 4; r++)
                op[(size_t)r * N_DIM] = acc[i][j][r];
        }
    }
}

extern "C" void kernel_launch(void* const* d_in, const int* in_sizes, int n_in,
                              void* d_out, int out_size, void* d_ws, size_t ws_size,
                              hipStream_t stream) {
    const float* x  = (const float*)d_in[0];
    const int*   qw = (const int*)d_in[1];
    const float* sc = (const float*)d_in[2];
    const int*   qz = (const int*)d_in[3];
    float* out = (float*)d_out;
    f16*   xh  = (f16*)d_ws;

    const bool pre = ws_size >= (size_t)M_DIM * K_DIM * sizeof(f16);  // 32 MB
    if (pre) {
        cvt_x<<<(M_DIM * K_DIM / 8) / 256, 256, 0, stream>>>(x, xh);
        gptq_gemm_big<<<dim3(N_DIM / BN, M_DIM / BM), 512, 0, stream>>>(xh, qw, sc, qz, out);
    } else {
        gptq_gemm_f32<<<dim3(N_DIM / 128, M_DIM / 128), 256, 0, stream>>>(x, qw, sc, qz, out);
    }
}